// Round 4
// baseline (4623.552 us; speedup 1.0000x reference)
//
#include <hip/hip_runtime.h>

// 6-layer GRU, T=512, B=256, I=128, H=256. ALL I/O IS FLOAT32. MFMA operands
// are converted f32->bf16 on the fly; h carried in f32; internal gx ws is bf16.
// d_out = [cur 512*256*256][finals 6*256*256] f32.
//
// Wavefront pipeline across (layer, chunk): per slot s launch ONE batched
// gx_gemm (blockIdx.z = pair) then ONE batched gru_scan (blockIdx.y = pair).
// Single-stream ordering supplies every dependency.
//
// SCAN v5 (this round): R3 showed the step is LDS-BW bound, not VALU bound --
// the n-gate weights in LDS cost 128KB of ds_read per WG per STEP (re-read
// every step), 2350+ cyc of LDS pipe time. Fix: ALL W_hh fragments back in
// VGPRs (bw[6][8] = 192 regs) under the real 256-reg budget of (512,1):
//  - pf single-buffered (12 regs), prefetch issued AFTER pointwise (latency
//    window = barrier + next MFMA phase, ~700 cyc).
//  - af not kept across loops: kt-loop = 1 ds_read + 6 reg-resident MFMAs.
//  - LDS = 16KB static h double-buffer only; per-step LDS 200KB -> 72KB.
//  - exp2 prefold kept (gx,Whh r/z pre-scaled log2e; n by 2log2e; bhn folded
//    into acc init). lgkmcnt-only barrier kept (vmcnt open across steps).

#define NLAY 6

typedef __bf16 bf16x8 __attribute__((ext_vector_type(8)));
typedef float  f32x4  __attribute__((ext_vector_type(4)));

typedef const unsigned int __attribute__((address_space(1)))* gp1_t;
typedef unsigned int __attribute__((address_space(3)))* lp3_t;

#define LOG2E  1.44269504088896340736f
#define LOG2E2 2.88539008177792681472f

__device__ __forceinline__ float b2f(unsigned short u) {
  union { unsigned int i; float f; } v; v.i = ((unsigned int)u) << 16; return v.f;
}
__device__ __forceinline__ unsigned short f2bs(float f) {
  union { __bf16 b; unsigned short s; } v; v.b = (__bf16)f; return v.s;
}
__device__ __forceinline__ bf16x8 cvt8(f32x4 lo, f32x4 hi) {
  bf16x8 r;
#pragma unroll
  for (int i = 0; i < 4; ++i) { r[i] = (__bf16)lo[i]; r[4 + i] = (__bf16)hi[i]; }
  return r;
}
__device__ __forceinline__ bf16x8 cvt8s(f32x4 lo, f32x4 hi, float s) {
  bf16x8 r;
#pragma unroll
  for (int i = 0; i < 4; ++i) { r[i] = (__bf16)(lo[i] * s); r[4 + i] = (__bf16)(hi[i] * s); }
  return r;
}

struct GemmBatch {
  const float* X[NLAY];
  const float* W[NLAY];
  const float* bih[NLAY];
  const float* bhh[NLAY];
  unsigned short* GX[NLAY];
  int K[NLAY];
};

// ---------------------------------------------------------------------------
// gx[m,g] = (sum_k X[m,k]*W[g,k] + bias(g)) * scale(g);  m = t*256+b
// scale = log2e for gates r,z (g<512), 2*log2e for gate n (exp2 prefold).
// X: [M][K] f32 row-major, W: [768][K] f32 row-major, K in {128,256}.
// GX (bf16): (t,b,g) -> GX[((t*16 + (b>>4))*768 + g)*16 + (b&15)]
// grid = (Tc*2, 6, npairs), block = 256. LDS slabs [128 rows][32 k] f32, 8
// 16B-groups per row; physical group g holds logical group g ^ (row&7).
// ---------------------------------------------------------------------------
__global__ __launch_bounds__(256) void gx_gemm(GemmBatch args)
{
  __shared__ __align__(16) float Asf[128 * 32];
  __shared__ __align__(16) float Bsf[128 * 32];
  const int p = blockIdx.z;
  const float* __restrict__ X  = args.X[p];
  const float* __restrict__ W  = args.W[p];
  const float* __restrict__ bihp = args.bih[p];
  const float* __restrict__ bhhp = args.bhh[p];
  unsigned short* __restrict__ GX = args.GX[p];
  const int K = args.K[p];

  const int tid  = threadIdx.x;
  const int lane = tid & 63;
  const int w    = tid >> 6;           // wave 0..3
  const int wy   = w >> 1, wx = w & 1; // 2x2 wave grid, 64x64 per wave
  const int l15  = lane & 15, q = lane >> 4;
  const int m0   = blockIdx.x * 128;
  const int n0   = blockIdx.y * 128;

  f32x4 acc[4][4];
#pragma unroll
  for (int a = 0; a < 4; ++a)
#pragma unroll
    for (int b = 0; b < 4; ++b) acc[a][b] = f32x4{0.f, 0.f, 0.f, 0.f};

  const int kiters = K >> 5;
  for (int kt = 0; kt < kiters; ++kt) {
    // stage: 1024 16B-chunks per slab (128 rows x 8 groups of 4 floats)
#pragma unroll
    for (int i = 0; i < 4; ++i) {
      int ci  = (w * 4 + i) * 64 + lane;   // 0..1023
      int row = ci >> 3;
      int g   = ci & 7;
      int kg  = g ^ (row & 7);
      const float* srcA = X + (size_t)(m0 + row) * K + kt * 32 + kg * 4;
      const float* srcB = W + (size_t)(n0 + row) * K + kt * 32 + kg * 4;
      __builtin_amdgcn_global_load_lds((gp1_t)(const void*)srcA,
          (lp3_t)(void*)((char*)Asf + (w * 4 + i) * 1024), 16, 0, 0);
      __builtin_amdgcn_global_load_lds((gp1_t)(const void*)srcB,
          (lp3_t)(void*)((char*)Bsf + (w * 4 + i) * 1024), 16, 0, 0);
    }
    __syncthreads();

    bf16x8 a[4], b[4];
#pragma unroll
    for (int tm = 0; tm < 4; ++tm) {
      int row = wy * 64 + tm * 16 + l15;
      int p0  = (2 * q) ^ (row & 7);
      int p1  = (2 * q + 1) ^ (row & 7);
      f32x4 lo = *(const f32x4*)(Asf + row * 32 + p0 * 4);
      f32x4 hi = *(const f32x4*)(Asf + row * 32 + p1 * 4);
      a[tm] = cvt8(lo, hi);
    }
#pragma unroll
    for (int tn = 0; tn < 4; ++tn) {
      int row = wx * 64 + tn * 16 + l15;
      int p0  = (2 * q) ^ (row & 7);
      int p1  = (2 * q + 1) ^ (row & 7);
      f32x4 lo = *(const f32x4*)(Bsf + row * 32 + p0 * 4);
      f32x4 hi = *(const f32x4*)(Bsf + row * 32 + p1 * 4);
      b[tn] = cvt8(lo, hi);
    }
#pragma unroll
    for (int tm = 0; tm < 4; ++tm)
#pragma unroll
      for (int tn = 0; tn < 4; ++tn)
        acc[tm][tn] = __builtin_amdgcn_mfma_f32_16x16x32_bf16(a[tm], b[tn], acc[tm][tn], 0, 0, 0);
    __syncthreads();
  }

  // epilogue: bias add (+b_hh folded for r,z), exp2-prefold scale, bf16, permuted
#pragma unroll
  for (int tn = 0; tn < 4; ++tn) {
    int g = n0 + wx * 64 + tn * 16 + l15;
    float bias = bihp[g] + (g < 512 ? bhhp[g] : 0.f);
    float scl  = (g < 512) ? LOG2E : LOG2E2;
#pragma unroll
    for (int tm = 0; tm < 4; ++tm) {
#pragma unroll
      for (int r = 0; r < 4; ++r) {
        int m = m0 + wy * 64 + tm * 16 + q * 4 + r;  // C row = 4*q + r
        int t = m >> 8, bb = m & 255;
        size_t dst = ((size_t)(t * 16 + (bb >> 4)) * 768 + g) * 16 + (bb & 15);
        GX[dst] = f2bs((acc[tm][tn][r] + bias) * scl);
      }
    }
  }
}

struct ScanBatch {
  const unsigned short* GX[NLAY];
  const float* Whh[NLAY];
  const float* bhh[NLAY];
  float* hcar[NLAY];
  const float* h0[NLAY];
  float* Y[NLAY];
  float* FIN[NLAY];
  int first[NLAY];
  int Tc;
};

// ---------------------------------------------------------------------------
// Recurrent scan. grid = (16, npairs). 8 waves; wave w owns gh columns
// [32w,32w+32) for all 3 gates. ALL W_hh bf16 B-fragments resident in VGPRs
// (bw[6][8] = 192 regs; r,z pre-scaled log2e, n pre-scaled 2log2e). h in f32
// regs; bf16 h in double-buffered swizzled LDS (A-op), 16KB static.
// Per step: [8x (ds_read af + 6 MFMA)] -> pointwise -> prefetch gx(t+1)
// (single pf buffer) -> lgkm-only barrier.
// ---------------------------------------------------------------------------
__global__ __launch_bounds__(512, 1) void gru_scan(ScanBatch args)
{
  __shared__ __align__(16) unsigned short hl[2 * 4096];  // bf16 h, dbuf, swizzled

  const int p = blockIdx.y;
  const unsigned short* __restrict__ GX = args.GX[p];
  const float* __restrict__ Whh = args.Whh[p];
  const float* __restrict__ bhh = args.bhh[p];
  float* __restrict__ hcar = args.hcar[p];
  const float* __restrict__ h0 = args.h0[p];
  float* __restrict__ Y = args.Y[p];
  float* __restrict__ FIN = args.FIN[p];
  const int Tc = args.Tc;
  const int first = args.first[p];

  const int wg  = blockIdx.x;
  const int b0  = wg << 4;
  const int tid = threadIdx.x;
  const int lane = tid & 63;
  const int w  = tid >> 6;       // 0..7
  const int m  = lane & 15;
  const int q  = lane >> 4;
  const int jb = w * 32 + m;     // j col base (c adds 16)

  // ALL W_hh B-fragments resident in VGPRs: B[k][n], n=l15 row, k=kt*32+8q+i.
  // gates r,z pre-scaled by log2e; gate n by 2*log2e (exp2 prefold).
  bf16x8 bw[6][8];
#pragma unroll
  for (int gate = 0; gate < 3; ++gate) {
    float scl = (gate < 2) ? LOG2E : LOG2E2;
#pragma unroll
    for (int c = 0; c < 2; ++c) {
      int n = gate * 256 + jb + c * 16;
#pragma unroll
      for (int kt = 0; kt < 8; ++kt) {
        f32x4 lo = *(const f32x4*)(Whh + (size_t)n * 256 + kt * 32 + q * 8);
        f32x4 hi = *(const f32x4*)(Whh + (size_t)n * 256 + kt * 32 + q * 8 + 4);
        bw[gate * 2 + c][kt] = cvt8s(lo, hi, scl);
      }
    }
  }

  float bhn[2];   // pre-scaled by 2log2e; folded into acc[4,5] init
#pragma unroll
  for (int c = 0; c < 2; ++c) bhn[c] = bhh[512 + jb + c * 16] * LOG2E2;

  // h registers: rows b0+4q+r, cols jb+16c
  float h[2][4];
#pragma unroll
  for (int c = 0; c < 2; ++c)
#pragma unroll
    for (int r = 0; r < 4; ++r) {
      int bb = b0 + q * 4 + r;
      int j  = jb + c * 16;
      h[c][r] = first ? h0[bb * 256 + j] : hcar[bb * 256 + j];
    }

  // init LDS h buf 0 (swizzle: addr = b*256 + (((j>>3)^(b&7))<<3) + (j&7))
#pragma unroll
  for (int c = 0; c < 2; ++c)
#pragma unroll
    for (int r = 0; r < 4; ++r) {
      int bb = q * 4 + r;
      int j  = jb + c * 16;
      int ad = bb * 256 + ((((j >> 3) ^ (bb & 7))) << 3) + (j & 7);
      hl[ad] = f2bs(h[c][r]);
    }

  // gx prefetch for t=0 (rows 4q..4q+3 at col g, 8B coalesced); single buffer
  const unsigned short* gpf = GX + ((size_t)wg * 768 + jb) * 16 + q * 4;
  ushort4 pf[6];
  pf[0] = *(const ushort4*)(gpf);
  pf[1] = *(const ushort4*)(gpf + 256);
  pf[2] = *(const ushort4*)(gpf + 4096);
  pf[3] = *(const ushort4*)(gpf + 4096 + 256);
  pf[4] = *(const ushort4*)(gpf + 8192);
  pf[5] = *(const ushort4*)(gpf + 8192 + 256);
  gpf += 196608;

  float* yp = Y + (size_t)(b0 + q * 4) * 256 + jb;
  __syncthreads();

  for (int t = 0; t < Tc; ++t) {
    // ---- gh = bf16(h) @ W_hh^T: 8x (1 ds_read_b128 + 6 reg-resident MFMA) --
    f32x4 acc[6];
#pragma unroll
    for (int i = 0; i < 4; ++i) acc[i] = f32x4{0.f, 0.f, 0.f, 0.f};
    acc[4] = f32x4{bhn[0], bhn[0], bhn[0], bhn[0]};
    acc[5] = f32x4{bhn[1], bhn[1], bhn[1], bhn[1]};
    {
      const unsigned short* hb = hl + (t & 1) * 4096;
#pragma unroll
      for (int kt = 0; kt < 8; ++kt) {
        int ad = m * 256 + (((kt * 4 + q) ^ (m & 7)) << 3);
        bf16x8 af = *(const bf16x8*)(hb + ad);
        acc[0] = __builtin_amdgcn_mfma_f32_16x16x32_bf16(af, bw[0][kt], acc[0], 0, 0, 0);
        acc[1] = __builtin_amdgcn_mfma_f32_16x16x32_bf16(af, bw[1][kt], acc[1], 0, 0, 0);
        acc[2] = __builtin_amdgcn_mfma_f32_16x16x32_bf16(af, bw[2][kt], acc[2], 0, 0, 0);
        acc[3] = __builtin_amdgcn_mfma_f32_16x16x32_bf16(af, bw[3][kt], acc[3], 0, 0, 0);
        acc[4] = __builtin_amdgcn_mfma_f32_16x16x32_bf16(af, bw[4][kt], acc[4], 0, 0, 0);
        acc[5] = __builtin_amdgcn_mfma_f32_16x16x32_bf16(af, bw[5][kt], acc[5], 0, 0, 0);
      }
    }

    // ---- pointwise GRU cell (exp2-prefolded), write next-h to other buffer --
    {
      unsigned short* hw = hl + ((t + 1) & 1) * 4096;
#pragma unroll
      for (int c = 0; c < 2; ++c) {
        ushort4 pr4 = pf[c];
        ushort4 pz4 = pf[2 + c];
        ushort4 pn4 = pf[4 + c];
#pragma unroll
        for (int r = 0; r < 4; ++r) {
          unsigned short pru = (r == 0) ? pr4.x : (r == 1) ? pr4.y : (r == 2) ? pr4.z : pr4.w;
          unsigned short pzu = (r == 0) ? pz4.x : (r == 1) ? pz4.y : (r == 2) ? pz4.z : pz4.w;
          unsigned short pnu = (r == 0) ? pn4.x : (r == 1) ? pn4.y : (r == 2) ? pn4.z : pn4.w;
          float ir  = b2f(pru);   /* log2e * (i_r + b) */
          float iz  = b2f(pzu);   /* log2e * (i_z + b) */
          float inn = b2f(pnu);   /* 2log2e * (i_n + b_ih) */
          float xr = ir + acc[c][r];
          float rr = __builtin_amdgcn_rcpf(1.f + __builtin_amdgcn_exp2f(-xr));
          float xz = iz + acc[2 + c][r];
          float zz = __builtin_amdgcn_rcpf(1.f + __builtin_amdgcn_exp2f(-xz));
          float nx = __builtin_fmaf(rr, acc[4 + c][r], inn);
          float e2 = __builtin_amdgcn_exp2f(nx);
          float nn = __builtin_fmaf(-2.f, __builtin_amdgcn_rcpf(1.f + e2), 1.f);
          float hv = __builtin_fmaf(zz, h[c][r] - nn, nn);
          h[c][r] = hv;
          int bb = q * 4 + r;
          int j  = jb + c * 16;
          int ad = bb * 256 + ((((j >> 3) ^ (bb & 7))) << 3) + (j & 7);
          hw[ad] = f2bs(hv);
          yp[r * 256 + c * 16] = hv;
        }
      }
    }

    // ---- prefetch gx(t+1) into pf (pf dead after pointwise; latency hides
    //      under barrier + next step's MFMA phase) ----
    if (t + 1 < Tc) {
      pf[0] = *(const ushort4*)(gpf);
      pf[1] = *(const ushort4*)(gpf + 256);
      pf[2] = *(const ushort4*)(gpf + 4096);
      pf[3] = *(const ushort4*)(gpf + 4096 + 256);
      pf[4] = *(const ushort4*)(gpf + 8192);
      pf[5] = *(const ushort4*)(gpf + 8192 + 256);
      gpf += 196608;
    }
    yp += 65536;
    asm volatile("s_waitcnt lgkmcnt(0)\n\ts_barrier" ::: "memory");
  }

  // carry out (f32) or finals (f32)
#pragma unroll
  for (int c = 0; c < 2; ++c)
#pragma unroll
    for (int r = 0; r < 4; ++r) {
      int bb = b0 + q * 4 + r;
      int j  = jb + c * 16;
      if (FIN) FIN[bb * 256 + j] = h[c][r];
      else     hcar[bb * 256 + j] = h[c][r];
    }
}

// ---------------------------------------------------------------------------
extern "C" void kernel_launch(void* const* d_in, const int* in_sizes, int n_in,
                              void* d_out, int out_size, void* d_ws, size_t ws_size,
                              hipStream_t stream) {
  const float* x    = (const float*)d_in[0]; // [512][256][128]
  const float* h0   = (const float*)d_in[1]; // [6][256][256]
  const float* Wih0 = (const float*)d_in[2]; // [768][128]
  const float* Wih  = (const float*)d_in[3]; // [5][768][256]
  const float* Whh  = (const float*)d_in[4]; // [6][768][256]
  const float* bih  = (const float*)d_in[5]; // [6][768]
  const float* bhh  = (const float*)d_in[6]; // [6][768]
  float* out = (float*)d_out;

  // largest Tc (<=32) whose ws fits NLAY gx buffers + NLAY carries.
  // gx per layer = Tc*16*768*16*2 B = Tc*393216 B; hcar per layer = 256KB.
  int Tc = 32;
  while (Tc > 4) {
    size_t need = (size_t)NLAY * Tc * 393216ull + (size_t)NLAY * 262144ull;
    if (need <= ws_size) break;
    Tc >>= 1;
  }
  const int nch = 512 / Tc;
  const size_t gxElems = (size_t)Tc * 196608;   // ushorts per layer buffer

  char* ws = (char*)d_ws;
  unsigned short* gx0   = (unsigned short*)ws;
  float*          hcar0 = (float*)(ws + (size_t)NLAY * Tc * 393216ull);

  float* cur = out;                              // [512][256][256] f32
  float* fin = out + (size_t)512 * 256 * 256;    // [6][256][256] f32

  const int nslots = NLAY + nch - 1;
  for (int s = 0; s < nslots; ++s) {
    int lmin = s - (nch - 1); if (lmin < 0) lmin = 0;
    int lmax = (s < NLAY - 1) ? s : (NLAY - 1);

    GemmBatch gb = {};
    ScanBatch sb = {};
    int np = 0;
    for (int l = lmin; l <= lmax; ++l, ++np) {
      int c = s - l;
      gb.X[np]   = (l == 0) ? (x + (size_t)c * Tc * 256 * 128)
                            : (cur + (size_t)c * Tc * 65536);
      gb.W[np]   = (l == 0) ? Wih0 : (Wih + (size_t)(l - 1) * 768 * 256);
      gb.bih[np] = bih + l * 768;
      gb.bhh[np] = bhh + l * 768;
      gb.GX[np]  = gx0 + (size_t)l * gxElems;
      gb.K[np]   = (l == 0) ? 128 : 256;

      sb.GX[np]    = gb.GX[np];
      sb.Whh[np]   = Whh + (size_t)l * 768 * 256;
      sb.bhh[np]   = bhh + l * 768;
      sb.hcar[np]  = hcar0 + (size_t)l * 65536;
      sb.h0[np]    = h0 + (size_t)l * 65536;
      sb.Y[np]     = cur + (size_t)c * Tc * 65536;
      sb.FIN[np]   = (c == nch - 1) ? (fin + (size_t)l * 65536) : (float*)nullptr;
      sb.first[np] = (c == 0) ? 1 : 0;
    }
    sb.Tc = Tc;

    gx_gemm<<<dim3(Tc * 2, 6, np), dim3(256), 0, stream>>>(gb);
    gru_scan<<<dim3(16, np), dim3(512), 0, stream>>>(sb);
  }
  (void)in_sizes; (void)n_in; (void)out_size; (void)ws_size;
}

// Round 5
// 4453.302 us; speedup vs baseline: 1.0382x; 1.0382x over previous
//
#include <hip/hip_runtime.h>

// 6-layer GRU, T=512, B=256, I=128, H=256. ALL I/O IS FLOAT32. MFMA operands
// are converted f32->bf16 on the fly; h carried in f32; internal gx ws is bf16.
// d_out = [cur 512*256*256][finals 6*256*256] f32.
//
// Wavefront pipeline across (layer, chunk): per slot s launch ONE batched
// gx_gemm (blockIdx.z = pair) then ONE batched gru_scan (blockIdx.y = pair).
// Single-stream ordering supplies every dependency.
//
// SCAN v6 (this round): R4 proved __launch_bounds__(512,1) does NOT lift the
// compiler's 128-VGPR cap (VGPR_Count stayed 128; the 192-reg weight set
// spilled; steady scan = 199us = R1's spilled level). The register file DOES
// fit the whole W_hh bf16 set: 256 regs x 512 thr = 512KB/CU = 2 waves/SIMD,
// the HW limit. Fix: pin occupancy from ABOVE with the clang attribute
// amdgpu_waves_per_eu(2,2) -> allocator budget = 512/2 = 256 VGPRs.
//  - bw[6][8] (192 regs) all-resident; LDS = 16KB h double-buffer only.
//  - demand held ~250: single pf buffer; pointwise consumes pf into locals
//    then immediately re-issues t+1 loads (window = pointwise+barrier+MFMA
//    ~1000 cyc, covers HBM ~900 cyc with one buffer).
//  - exp2 prefold kept; lgkmcnt-only barrier kept (vmcnt open across steps).

#define NLAY 6

typedef __bf16 bf16x8 __attribute__((ext_vector_type(8)));
typedef float  f32x4  __attribute__((ext_vector_type(4)));

typedef const unsigned int __attribute__((address_space(1)))* gp1_t;
typedef unsigned int __attribute__((address_space(3)))* lp3_t;

#define LOG2E  1.44269504088896340736f
#define LOG2E2 2.88539008177792681472f

__device__ __forceinline__ float b2f(unsigned short u) {
  union { unsigned int i; float f; } v; v.i = ((unsigned int)u) << 16; return v.f;
}
__device__ __forceinline__ unsigned short f2bs(float f) {
  union { __bf16 b; unsigned short s; } v; v.b = (__bf16)f; return v.s;
}
__device__ __forceinline__ bf16x8 cvt8(f32x4 lo, f32x4 hi) {
  bf16x8 r;
#pragma unroll
  for (int i = 0; i < 4; ++i) { r[i] = (__bf16)lo[i]; r[4 + i] = (__bf16)hi[i]; }
  return r;
}
__device__ __forceinline__ bf16x8 cvt8s(f32x4 lo, f32x4 hi, float s) {
  bf16x8 r;
#pragma unroll
  for (int i = 0; i < 4; ++i) { r[i] = (__bf16)(lo[i] * s); r[4 + i] = (__bf16)(hi[i] * s); }
  return r;
}

struct GemmBatch {
  const float* X[NLAY];
  const float* W[NLAY];
  const float* bih[NLAY];
  const float* bhh[NLAY];
  unsigned short* GX[NLAY];
  int K[NLAY];
};

// ---------------------------------------------------------------------------
// gx[m,g] = (sum_k X[m,k]*W[g,k] + bias(g)) * scale(g);  m = t*256+b
// scale = log2e for gates r,z (g<512), 2*log2e for gate n (exp2 prefold).
// X: [M][K] f32 row-major, W: [768][K] f32 row-major, K in {128,256}.
// GX (bf16): (t,b,g) -> GX[((t*16 + (b>>4))*768 + g)*16 + (b&15)]
// grid = (Tc*2, 6, npairs), block = 256. LDS slabs [128 rows][32 k] f32, 8
// 16B-groups per row; physical group g holds logical group g ^ (row&7).
// ---------------------------------------------------------------------------
__global__ __launch_bounds__(256) void gx_gemm(GemmBatch args)
{
  __shared__ __align__(16) float Asf[128 * 32];
  __shared__ __align__(16) float Bsf[128 * 32];
  const int p = blockIdx.z;
  const float* __restrict__ X  = args.X[p];
  const float* __restrict__ W  = args.W[p];
  const float* __restrict__ bihp = args.bih[p];
  const float* __restrict__ bhhp = args.bhh[p];
  unsigned short* __restrict__ GX = args.GX[p];
  const int K = args.K[p];

  const int tid  = threadIdx.x;
  const int lane = tid & 63;
  const int w    = tid >> 6;           // wave 0..3
  const int wy   = w >> 1, wx = w & 1; // 2x2 wave grid, 64x64 per wave
  const int l15  = lane & 15, q = lane >> 4;
  const int m0   = blockIdx.x * 128;
  const int n0   = blockIdx.y * 128;

  f32x4 acc[4][4];
#pragma unroll
  for (int a = 0; a < 4; ++a)
#pragma unroll
    for (int b = 0; b < 4; ++b) acc[a][b] = f32x4{0.f, 0.f, 0.f, 0.f};

  const int kiters = K >> 5;
  for (int kt = 0; kt < kiters; ++kt) {
    // stage: 1024 16B-chunks per slab (128 rows x 8 groups of 4 floats)
#pragma unroll
    for (int i = 0; i < 4; ++i) {
      int ci  = (w * 4 + i) * 64 + lane;   // 0..1023
      int row = ci >> 3;
      int g   = ci & 7;
      int kg  = g ^ (row & 7);
      const float* srcA = X + (size_t)(m0 + row) * K + kt * 32 + kg * 4;
      const float* srcB = W + (size_t)(n0 + row) * K + kt * 32 + kg * 4;
      __builtin_amdgcn_global_load_lds((gp1_t)(const void*)srcA,
          (lp3_t)(void*)((char*)Asf + (w * 4 + i) * 1024), 16, 0, 0);
      __builtin_amdgcn_global_load_lds((gp1_t)(const void*)srcB,
          (lp3_t)(void*)((char*)Bsf + (w * 4 + i) * 1024), 16, 0, 0);
    }
    __syncthreads();

    bf16x8 a[4], b[4];
#pragma unroll
    for (int tm = 0; tm < 4; ++tm) {
      int row = wy * 64 + tm * 16 + l15;
      int p0  = (2 * q) ^ (row & 7);
      int p1  = (2 * q + 1) ^ (row & 7);
      f32x4 lo = *(const f32x4*)(Asf + row * 32 + p0 * 4);
      f32x4 hi = *(const f32x4*)(Asf + row * 32 + p1 * 4);
      a[tm] = cvt8(lo, hi);
    }
#pragma unroll
    for (int tn = 0; tn < 4; ++tn) {
      int row = wx * 64 + tn * 16 + l15;
      int p0  = (2 * q) ^ (row & 7);
      int p1  = (2 * q + 1) ^ (row & 7);
      f32x4 lo = *(const f32x4*)(Bsf + row * 32 + p0 * 4);
      f32x4 hi = *(const f32x4*)(Bsf + row * 32 + p1 * 4);
      b[tn] = cvt8(lo, hi);
    }
#pragma unroll
    for (int tm = 0; tm < 4; ++tm)
#pragma unroll
      for (int tn = 0; tn < 4; ++tn)
        acc[tm][tn] = __builtin_amdgcn_mfma_f32_16x16x32_bf16(a[tm], b[tn], acc[tm][tn], 0, 0, 0);
    __syncthreads();
  }

  // epilogue: bias add (+b_hh folded for r,z), exp2-prefold scale, bf16, permuted
#pragma unroll
  for (int tn = 0; tn < 4; ++tn) {
    int g = n0 + wx * 64 + tn * 16 + l15;
    float bias = bihp[g] + (g < 512 ? bhhp[g] : 0.f);
    float scl  = (g < 512) ? LOG2E : LOG2E2;
#pragma unroll
    for (int tm = 0; tm < 4; ++tm) {
#pragma unroll
      for (int r = 0; r < 4; ++r) {
        int m = m0 + wy * 64 + tm * 16 + q * 4 + r;  // C row = 4*q + r
        int t = m >> 8, bb = m & 255;
        size_t dst = ((size_t)(t * 16 + (bb >> 4)) * 768 + g) * 16 + (bb & 15);
        GX[dst] = f2bs((acc[tm][tn][r] + bias) * scl);
      }
    }
  }
}

struct ScanBatch {
  const unsigned short* GX[NLAY];
  const float* Whh[NLAY];
  const float* bhh[NLAY];
  float* hcar[NLAY];
  const float* h0[NLAY];
  float* Y[NLAY];
  float* FIN[NLAY];
  int first[NLAY];
  int Tc;
};

// ---------------------------------------------------------------------------
// Recurrent scan. grid = (16, npairs). 8 waves; wave w owns gh columns
// [32w,32w+32) for all 3 gates. ALL W_hh bf16 B-fragments resident in VGPRs
// (bw[6][8] = 192 regs; r,z pre-scaled log2e, n pre-scaled 2log2e). h in f32
// regs; bf16 h in double-buffered swizzled LDS (A-op), 16KB static.
// amdgpu_waves_per_eu(2,2): 8-wave WG = exactly 2 waves/SIMD -> 256-VGPR
// budget, weights stay resident (the whole point of this round).
// Per step: [8x (ds_read af + 6 MFMA)] -> {pf->locals; issue prefetch t+1}
// -> pointwise -> lgkm-only barrier.
// ---------------------------------------------------------------------------
__global__ __attribute__((amdgpu_flat_work_group_size(512, 512),
                          amdgpu_waves_per_eu(2, 2)))
void gru_scan(ScanBatch args)
{
  __shared__ __align__(16) unsigned short hl[2 * 4096];  // bf16 h, dbuf, swizzled

  const int p = blockIdx.y;
  const unsigned short* __restrict__ GX = args.GX[p];
  const float* __restrict__ Whh = args.Whh[p];
  const float* __restrict__ bhh = args.bhh[p];
  float* __restrict__ hcar = args.hcar[p];
  const float* __restrict__ h0 = args.h0[p];
  float* __restrict__ Y = args.Y[p];
  float* __restrict__ FIN = args.FIN[p];
  const int Tc = args.Tc;
  const int first = args.first[p];

  const int wg  = blockIdx.x;
  const int b0  = wg << 4;
  const int tid = threadIdx.x;
  const int lane = tid & 63;
  const int w  = tid >> 6;       // 0..7
  const int m  = lane & 15;
  const int q  = lane >> 4;
  const int jb = w * 32 + m;     // j col base (c adds 16)

  // ALL W_hh B-fragments resident in VGPRs: B[k][n], n=l15 row, k=kt*32+8q+i.
  // gates r,z pre-scaled by log2e; gate n by 2*log2e (exp2 prefold).
  bf16x8 bw[6][8];
#pragma unroll
  for (int gate = 0; gate < 3; ++gate) {
    float scl = (gate < 2) ? LOG2E : LOG2E2;
#pragma unroll
    for (int c = 0; c < 2; ++c) {
      int n = gate * 256 + jb + c * 16;
#pragma unroll
      for (int kt = 0; kt < 8; ++kt) {
        f32x4 lo = *(const f32x4*)(Whh + (size_t)n * 256 + kt * 32 + q * 8);
        f32x4 hi = *(const f32x4*)(Whh + (size_t)n * 256 + kt * 32 + q * 8 + 4);
        bw[gate * 2 + c][kt] = cvt8s(lo, hi, scl);
      }
    }
  }

  float bhn[2];   // pre-scaled by 2log2e; folded into acc[4,5] init
#pragma unroll
  for (int c = 0; c < 2; ++c) bhn[c] = bhh[512 + jb + c * 16] * LOG2E2;

  // h registers: rows b0+4q+r, cols jb+16c
  float h[2][4];
#pragma unroll
  for (int c = 0; c < 2; ++c)
#pragma unroll
    for (int r = 0; r < 4; ++r) {
      int bb = b0 + q * 4 + r;
      int j  = jb + c * 16;
      h[c][r] = first ? h0[bb * 256 + j] : hcar[bb * 256 + j];
    }

  // init LDS h buf 0 (swizzle: addr = b*256 + (((j>>3)^(b&7))<<3) + (j&7))
#pragma unroll
  for (int c = 0; c < 2; ++c)
#pragma unroll
    for (int r = 0; r < 4; ++r) {
      int bb = q * 4 + r;
      int j  = jb + c * 16;
      int ad = bb * 256 + ((((j >> 3) ^ (bb & 7))) << 3) + (j & 7);
      hl[ad] = f2bs(h[c][r]);
    }

  // gx prefetch for t=0 (rows 4q..4q+3 at col g, 8B coalesced); single buffer
  const unsigned short* gpf = GX + ((size_t)wg * 768 + jb) * 16 + q * 4;
  ushort4 pf[6];
  pf[0] = *(const ushort4*)(gpf);
  pf[1] = *(const ushort4*)(gpf + 256);
  pf[2] = *(const ushort4*)(gpf + 4096);
  pf[3] = *(const ushort4*)(gpf + 4096 + 256);
  pf[4] = *(const ushort4*)(gpf + 8192);
  pf[5] = *(const ushort4*)(gpf + 8192 + 256);
  gpf += 196608;

  float* yp = Y + (size_t)(b0 + q * 4) * 256 + jb;
  __syncthreads();

  for (int t = 0; t < Tc; ++t) {
    // ---- gh = bf16(h) @ W_hh^T: 8x (1 ds_read_b128 + 6 reg-resident MFMA) --
    f32x4 acc[6];
#pragma unroll
    for (int i = 0; i < 4; ++i) acc[i] = f32x4{0.f, 0.f, 0.f, 0.f};
    acc[4] = f32x4{bhn[0], bhn[0], bhn[0], bhn[0]};
    acc[5] = f32x4{bhn[1], bhn[1], bhn[1], bhn[1]};
    {
      const unsigned short* hb = hl + (t & 1) * 4096;
#pragma unroll
      for (int kt = 0; kt < 8; ++kt) {
        int ad = m * 256 + (((kt * 4 + q) ^ (m & 7)) << 3);
        bf16x8 af = *(const bf16x8*)(hb + ad);
        acc[0] = __builtin_amdgcn_mfma_f32_16x16x32_bf16(af, bw[0][kt], acc[0], 0, 0, 0);
        acc[1] = __builtin_amdgcn_mfma_f32_16x16x32_bf16(af, bw[1][kt], acc[1], 0, 0, 0);
        acc[2] = __builtin_amdgcn_mfma_f32_16x16x32_bf16(af, bw[2][kt], acc[2], 0, 0, 0);
        acc[3] = __builtin_amdgcn_mfma_f32_16x16x32_bf16(af, bw[3][kt], acc[3], 0, 0, 0);
        acc[4] = __builtin_amdgcn_mfma_f32_16x16x32_bf16(af, bw[4][kt], acc[4], 0, 0, 0);
        acc[5] = __builtin_amdgcn_mfma_f32_16x16x32_bf16(af, bw[5][kt], acc[5], 0, 0, 0);
      }
    }

    // ---- move pf to locals, immediately issue prefetch of gx(t+1): the
    //      loads' consumer is NEXT step's pointwise -> window = this
    //      pointwise + barrier + next MFMA phase (~1000 cyc, covers HBM) ----
    ushort4 c0 = pf[0], c1 = pf[1], c2 = pf[2], c3 = pf[3], c4 = pf[4], c5 = pf[5];
    if (t + 1 < Tc) {
      pf[0] = *(const ushort4*)(gpf);
      pf[1] = *(const ushort4*)(gpf + 256);
      pf[2] = *(const ushort4*)(gpf + 4096);
      pf[3] = *(const ushort4*)(gpf + 4096 + 256);
      pf[4] = *(const ushort4*)(gpf + 8192);
      pf[5] = *(const ushort4*)(gpf + 8192 + 256);
      gpf += 196608;
    }

    // ---- pointwise GRU cell (exp2-prefolded), write next-h to other buffer --
    {
      unsigned short* hw = hl + ((t + 1) & 1) * 4096;
#pragma unroll
      for (int c = 0; c < 2; ++c) {
        ushort4 pr4 = (c == 0) ? c0 : c1;
        ushort4 pz4 = (c == 0) ? c2 : c3;
        ushort4 pn4 = (c == 0) ? c4 : c5;
#pragma unroll
        for (int r = 0; r < 4; ++r) {
          unsigned short pru = (r == 0) ? pr4.x : (r == 1) ? pr4.y : (r == 2) ? pr4.z : pr4.w;
          unsigned short pzu = (r == 0) ? pz4.x : (r == 1) ? pz4.y : (r == 2) ? pz4.z : pz4.w;
          unsigned short pnu = (r == 0) ? pn4.x : (r == 1) ? pn4.y : (r == 2) ? pn4.z : pn4.w;
          float ir  = b2f(pru);   /* log2e * (i_r + b) */
          float iz  = b2f(pzu);   /* log2e * (i_z + b) */
          float inn = b2f(pnu);   /* 2log2e * (i_n + b_ih) */
          float xr = ir + acc[c][r];
          float rr = __builtin_amdgcn_rcpf(1.f + __builtin_amdgcn_exp2f(-xr));
          float xz = iz + acc[2 + c][r];
          float zz = __builtin_amdgcn_rcpf(1.f + __builtin_amdgcn_exp2f(-xz));
          float nx = __builtin_fmaf(rr, acc[4 + c][r], inn);
          float e2 = __builtin_amdgcn_exp2f(nx);
          float nn = __builtin_fmaf(-2.f, __builtin_amdgcn_rcpf(1.f + e2), 1.f);
          float hv = __builtin_fmaf(zz, h[c][r] - nn, nn);
          h[c][r] = hv;
          int bb = q * 4 + r;
          int j  = jb + c * 16;
          int ad = bb * 256 + ((((j >> 3) ^ (bb & 7))) << 3) + (j & 7);
          hw[ad] = f2bs(hv);
          yp[r * 256 + c * 16] = hv;
        }
      }
    }

    yp += 65536;
    asm volatile("s_waitcnt lgkmcnt(0)\n\ts_barrier" ::: "memory");
  }

  // carry out (f32) or finals (f32)
#pragma unroll
  for (int c = 0; c < 2; ++c)
#pragma unroll
    for (int r = 0; r < 4; ++r) {
      int bb = b0 + q * 4 + r;
      int j  = jb + c * 16;
      if (FIN) FIN[bb * 256 + j] = h[c][r];
      else     hcar[bb * 256 + j] = h[c][r];
    }
}

// ---------------------------------------------------------------------------
extern "C" void kernel_launch(void* const* d_in, const int* in_sizes, int n_in,
                              void* d_out, int out_size, void* d_ws, size_t ws_size,
                              hipStream_t stream) {
  const float* x    = (const float*)d_in[0]; // [512][256][128]
  const float* h0   = (const float*)d_in[1]; // [6][256][256]
  const float* Wih0 = (const float*)d_in[2]; // [768][128]
  const float* Wih  = (const float*)d_in[3]; // [5][768][256]
  const float* Whh  = (const float*)d_in[4]; // [6][768][256]
  const float* bih  = (const float*)d_in[5]; // [6][768]
  const float* bhh  = (const float*)d_in[6]; // [6][768]
  float* out = (float*)d_out;

  // largest Tc (<=32) whose ws fits NLAY gx buffers + NLAY carries.
  // gx per layer = Tc*16*768*16*2 B = Tc*393216 B; hcar per layer = 256KB.
  int Tc = 32;
  while (Tc > 4) {
    size_t need = (size_t)NLAY * Tc * 393216ull + (size_t)NLAY * 262144ull;
    if (need <= ws_size) break;
    Tc >>= 1;
  }
  const int nch = 512 / Tc;
  const size_t gxElems = (size_t)Tc * 196608;   // ushorts per layer buffer

  char* ws = (char*)d_ws;
  unsigned short* gx0   = (unsigned short*)ws;
  float*          hcar0 = (float*)(ws + (size_t)NLAY * Tc * 393216ull);

  float* cur = out;                              // [512][256][256] f32
  float* fin = out + (size_t)512 * 256 * 256;    // [6][256][256] f32

  const int nslots = NLAY + nch - 1;
  for (int s = 0; s < nslots; ++s) {
    int lmin = s - (nch - 1); if (lmin < 0) lmin = 0;
    int lmax = (s < NLAY - 1) ? s : (NLAY - 1);

    GemmBatch gb = {};
    ScanBatch sb = {};
    int np = 0;
    for (int l = lmin; l <= lmax; ++l, ++np) {
      int c = s - l;
      gb.X[np]   = (l == 0) ? (x + (size_t)c * Tc * 256 * 128)
                            : (cur + (size_t)c * Tc * 65536);
      gb.W[np]   = (l == 0) ? Wih0 : (Wih + (size_t)(l - 1) * 768 * 256);
      gb.bih[np] = bih + l * 768;
      gb.bhh[np] = bhh + l * 768;
      gb.GX[np]  = gx0 + (size_t)l * gxElems;
      gb.K[np]   = (l == 0) ? 128 : 256;

      sb.GX[np]    = gb.GX[np];
      sb.Whh[np]   = Whh + (size_t)l * 768 * 256;
      sb.bhh[np]   = bhh + l * 768;
      sb.hcar[np]  = hcar0 + (size_t)l * 65536;
      sb.h0[np]    = h0 + (size_t)l * 65536;
      sb.Y[np]     = cur + (size_t)c * Tc * 65536;
      sb.FIN[np]   = (c == nch - 1) ? (fin + (size_t)l * 65536) : (float*)nullptr;
      sb.first[np] = (c == 0) ? 1 : 0;
    }
    sb.Tc = Tc;

    gx_gemm<<<dim3(Tc * 2, 6, np), dim3(256), 0, stream>>>(gb);
    gru_scan<<<dim3(16, np), dim3(512), 0, stream>>>(sb);
  }
  (void)in_sizes; (void)n_in; (void)out_size; (void)ws_size;
}

// Round 6
// 3017.764 us; speedup vs baseline: 1.5321x; 1.4757x over previous
//
#include <hip/hip_runtime.h>

// 6-layer GRU, T=512, B=256, I=128, H=256. ALL I/O IS FLOAT32. MFMA operands
// are converted f32->bf16 on the fly; h carried in f32; internal gx ws is bf16.
// d_out = [cur 512*256*256][finals 6*256*256] f32.
//
// Wavefront pipeline across (layer, chunk): per slot s launch ONE batched
// gx_gemm (blockIdx.z = pair) then ONE batched gru_scan (blockIdx.y = pair).
// Single-stream ordering supplies every dependency.
//
// SCAN v7: REGISTER MODEL (from R2-R5 evidence): 8-wave WG => 2 waves/SIMD
// hardware floor => unified VGPR+AGPR budget = 256/wave, immovable. rocprof
// VGPR_Count=128 is arch-only; MFMA operands live in AGPRs. R3 (212 unified)
// ran clean; R1/R4/R5 (250-270) spilled. Full bw[6][8] residency (262+) can
// NOT fit. So: maximal residency within budget:
//  - bw[5][8] = 160 regs resident (r,z both tiles + n tile c=0);
//  - n tile c=1 from LDS (64KB buffer, 1 ds_read_b128/kt/wave = 64KB/step,
//    half of R3's n-gate traffic);
//  - pf single-buffered, consumed & reloaded IN PLACE per c-phase (no copies);
//  - unified demand ~235 < 256 => no spill (the bet of this round);
//  - exp2 prefold, lgkm-only barrier, 80KB dynamic LDS (hl 16K + wn 64K).

#define NLAY 6

typedef __bf16 bf16x8 __attribute__((ext_vector_type(8)));
typedef float  f32x4  __attribute__((ext_vector_type(4)));

typedef const unsigned int __attribute__((address_space(1)))* gp1_t;
typedef unsigned int __attribute__((address_space(3)))* lp3_t;

#define LOG2E  1.44269504088896340736f
#define LOG2E2 2.88539008177792681472f

__device__ __forceinline__ float b2f(unsigned short u) {
  union { unsigned int i; float f; } v; v.i = ((unsigned int)u) << 16; return v.f;
}
__device__ __forceinline__ unsigned short f2bs(float f) {
  union { __bf16 b; unsigned short s; } v; v.b = (__bf16)f; return v.s;
}
__device__ __forceinline__ bf16x8 cvt8(f32x4 lo, f32x4 hi) {
  bf16x8 r;
#pragma unroll
  for (int i = 0; i < 4; ++i) { r[i] = (__bf16)lo[i]; r[4 + i] = (__bf16)hi[i]; }
  return r;
}
__device__ __forceinline__ bf16x8 cvt8s(f32x4 lo, f32x4 hi, float s) {
  bf16x8 r;
#pragma unroll
  for (int i = 0; i < 4; ++i) { r[i] = (__bf16)(lo[i] * s); r[4 + i] = (__bf16)(hi[i] * s); }
  return r;
}

struct GemmBatch {
  const float* X[NLAY];
  const float* W[NLAY];
  const float* bih[NLAY];
  const float* bhh[NLAY];
  unsigned short* GX[NLAY];
  int K[NLAY];
};

// ---------------------------------------------------------------------------
// gx[m,g] = (sum_k X[m,k]*W[g,k] + bias(g)) * scale(g);  m = t*256+b
// scale = log2e for gates r,z (g<512), 2*log2e for gate n (exp2 prefold).
// X: [M][K] f32 row-major, W: [768][K] f32 row-major, K in {128,256}.
// GX (bf16): (t,b,g) -> GX[((t*16 + (b>>4))*768 + g)*16 + (b&15)]
// grid = (Tc*2, 6, npairs), block = 256. LDS slabs [128 rows][32 k] f32, 8
// 16B-groups per row; physical group g holds logical group g ^ (row&7).
// ---------------------------------------------------------------------------
__global__ __launch_bounds__(256) void gx_gemm(GemmBatch args)
{
  __shared__ __align__(16) float Asf[128 * 32];
  __shared__ __align__(16) float Bsf[128 * 32];
  const int p = blockIdx.z;
  const float* __restrict__ X  = args.X[p];
  const float* __restrict__ W  = args.W[p];
  const float* __restrict__ bihp = args.bih[p];
  const float* __restrict__ bhhp = args.bhh[p];
  unsigned short* __restrict__ GX = args.GX[p];
  const int K = args.K[p];

  const int tid  = threadIdx.x;
  const int lane = tid & 63;
  const int w    = tid >> 6;           // wave 0..3
  const int wy   = w >> 1, wx = w & 1; // 2x2 wave grid, 64x64 per wave
  const int l15  = lane & 15, q = lane >> 4;
  const int m0   = blockIdx.x * 128;
  const int n0   = blockIdx.y * 128;

  f32x4 acc[4][4];
#pragma unroll
  for (int a = 0; a < 4; ++a)
#pragma unroll
    for (int b = 0; b < 4; ++b) acc[a][b] = f32x4{0.f, 0.f, 0.f, 0.f};

  const int kiters = K >> 5;
  for (int kt = 0; kt < kiters; ++kt) {
    // stage: 1024 16B-chunks per slab (128 rows x 8 groups of 4 floats)
#pragma unroll
    for (int i = 0; i < 4; ++i) {
      int ci  = (w * 4 + i) * 64 + lane;   // 0..1023
      int row = ci >> 3;
      int g   = ci & 7;
      int kg  = g ^ (row & 7);
      const float* srcA = X + (size_t)(m0 + row) * K + kt * 32 + kg * 4;
      const float* srcB = W + (size_t)(n0 + row) * K + kt * 32 + kg * 4;
      __builtin_amdgcn_global_load_lds((gp1_t)(const void*)srcA,
          (lp3_t)(void*)((char*)Asf + (w * 4 + i) * 1024), 16, 0, 0);
      __builtin_amdgcn_global_load_lds((gp1_t)(const void*)srcB,
          (lp3_t)(void*)((char*)Bsf + (w * 4 + i) * 1024), 16, 0, 0);
    }
    __syncthreads();

    bf16x8 a[4], b[4];
#pragma unroll
    for (int tm = 0; tm < 4; ++tm) {
      int row = wy * 64 + tm * 16 + l15;
      int p0  = (2 * q) ^ (row & 7);
      int p1  = (2 * q + 1) ^ (row & 7);
      f32x4 lo = *(const f32x4*)(Asf + row * 32 + p0 * 4);
      f32x4 hi = *(const f32x4*)(Asf + row * 32 + p1 * 4);
      a[tm] = cvt8(lo, hi);
    }
#pragma unroll
    for (int tn = 0; tn < 4; ++tn) {
      int row = wx * 64 + tn * 16 + l15;
      int p0  = (2 * q) ^ (row & 7);
      int p1  = (2 * q + 1) ^ (row & 7);
      f32x4 lo = *(const f32x4*)(Bsf + row * 32 + p0 * 4);
      f32x4 hi = *(const f32x4*)(Bsf + row * 32 + p1 * 4);
      b[tn] = cvt8(lo, hi);
    }
#pragma unroll
    for (int tm = 0; tm < 4; ++tm)
#pragma unroll
      for (int tn = 0; tn < 4; ++tn)
        acc[tm][tn] = __builtin_amdgcn_mfma_f32_16x16x32_bf16(a[tm], b[tn], acc[tm][tn], 0, 0, 0);
    __syncthreads();
  }

  // epilogue: bias add (+b_hh folded for r,z), exp2-prefold scale, bf16, permuted
#pragma unroll
  for (int tn = 0; tn < 4; ++tn) {
    int g = n0 + wx * 64 + tn * 16 + l15;
    float bias = bihp[g] + (g < 512 ? bhhp[g] : 0.f);
    float scl  = (g < 512) ? LOG2E : LOG2E2;
#pragma unroll
    for (int tm = 0; tm < 4; ++tm) {
#pragma unroll
      for (int r = 0; r < 4; ++r) {
        int m = m0 + wy * 64 + tm * 16 + q * 4 + r;  // C row = 4*q + r
        int t = m >> 8, bb = m & 255;
        size_t dst = ((size_t)(t * 16 + (bb >> 4)) * 768 + g) * 16 + (bb & 15);
        GX[dst] = f2bs((acc[tm][tn][r] + bias) * scl);
      }
    }
  }
}

struct ScanBatch {
  const unsigned short* GX[NLAY];
  const float* Whh[NLAY];
  const float* bhh[NLAY];
  float* hcar[NLAY];
  const float* h0[NLAY];
  float* Y[NLAY];
  float* FIN[NLAY];
  int first[NLAY];
  int Tc;
};

// ---------------------------------------------------------------------------
// Recurrent scan. grid = (16, npairs). 8 waves; wave w owns gh columns
// [32w,32w+32) for all 3 gates. bw[5][8] (r,z both 16-col tiles + n tile c=0;
// 160 regs, AGPR-eligible) resident; n tile c=1 in LDS (64KB, per-lane
// contiguous, 1 ds_read_b128 per kt). h f32 in regs; bf16 h in double-
// buffered swizzled LDS (A-op). Dynamic LDS 80KB (hl 16K + wn 64K).
// Per step: [8x (ds_read af + ds_read w5 + 6 MFMA)] -> pointwise c=0 (uses
// pf[0,2,4], then reloads them for t+1) -> pointwise c=1 (pf[1,3,5], reload)
// -> lgkm-only barrier (vmcnt stays open).
// ---------------------------------------------------------------------------
__global__ __launch_bounds__(512, 1) void gru_scan(ScanBatch args)
{
  extern __shared__ __align__(16) char smem[];
  unsigned short* hl = (unsigned short*)smem;            // 2 x 16x256 bf16 (16KB)
  unsigned short* wn = (unsigned short*)(smem + 16384);  // [8 w][8 kt][64 lane][8] (64KB)

  const int p = blockIdx.y;
  const unsigned short* __restrict__ GX = args.GX[p];
  const float* __restrict__ Whh = args.Whh[p];
  const float* __restrict__ bhh = args.bhh[p];
  float* __restrict__ hcar = args.hcar[p];
  const float* __restrict__ h0 = args.h0[p];
  float* __restrict__ Y = args.Y[p];
  float* __restrict__ FIN = args.FIN[p];
  const int Tc = args.Tc;
  const int first = args.first[p];

  const int wg  = blockIdx.x;
  const int b0  = wg << 4;
  const int tid = threadIdx.x;
  const int lane = tid & 63;
  const int w  = tid >> 6;       // 0..7
  const int m  = lane & 15;
  const int q  = lane >> 4;
  const int jb = w * 32 + m;     // j col base (c adds 16)

  // Resident W_hh B-fragments: B[k][n], n=l15 row, k=kt*32+8q+i.
  // bw[0]=r/c0 bw[1]=r/c1 bw[2]=z/c0 bw[3]=z/c1 bw[4]=n/c0 (n/c1 -> LDS).
  // r,z pre-scaled by log2e; n by 2*log2e (exp2 prefold).
  bf16x8 bw[5][8];
#pragma unroll
  for (int gate = 0; gate < 2; ++gate)
#pragma unroll
    for (int c = 0; c < 2; ++c) {
      int n = gate * 256 + jb + c * 16;
#pragma unroll
      for (int kt = 0; kt < 8; ++kt) {
        f32x4 lo = *(const f32x4*)(Whh + (size_t)n * 256 + kt * 32 + q * 8);
        f32x4 hi = *(const f32x4*)(Whh + (size_t)n * 256 + kt * 32 + q * 8 + 4);
        bw[gate * 2 + c][kt] = cvt8s(lo, hi, LOG2E);
      }
    }
  {
    int n = 512 + jb;               // n-gate, c=0 tile resident
#pragma unroll
    for (int kt = 0; kt < 8; ++kt) {
      f32x4 lo = *(const f32x4*)(Whh + (size_t)n * 256 + kt * 32 + q * 8);
      f32x4 hi = *(const f32x4*)(Whh + (size_t)n * 256 + kt * 32 + q * 8 + 4);
      bw[4][kt] = cvt8s(lo, hi, LOG2E2);
    }
  }
  // n-gate c=1 tile -> LDS, per-lane contiguous (lane re-reads only its own
  // fragment; ds_read_b128 conflict-free; base + kt*1024B immediate offsets).
  {
    int n = 512 + jb + 16;
#pragma unroll
    for (int kt = 0; kt < 8; ++kt) {
      f32x4 lo = *(const f32x4*)(Whh + (size_t)n * 256 + kt * 32 + q * 8);
      f32x4 hi = *(const f32x4*)(Whh + (size_t)n * 256 + kt * 32 + q * 8 + 4);
      *(bf16x8*)(wn + ((size_t)(w * 8 + kt) * 64 + lane) * 8) = cvt8s(lo, hi, LOG2E2);
    }
  }
  const unsigned short* wnl = wn + ((size_t)w * 8 * 64 + lane) * 8;

  float bhn[2];   // pre-scaled by 2log2e; folded into acc[4,5] init
#pragma unroll
  for (int c = 0; c < 2; ++c) bhn[c] = bhh[512 + jb + c * 16] * LOG2E2;

  // h registers: rows b0+4q+r, cols jb+16c
  float h[2][4];
#pragma unroll
  for (int c = 0; c < 2; ++c)
#pragma unroll
    for (int r = 0; r < 4; ++r) {
      int bb = b0 + q * 4 + r;
      int j  = jb + c * 16;
      h[c][r] = first ? h0[bb * 256 + j] : hcar[bb * 256 + j];
    }

  // init LDS h buf 0 (swizzle: addr = b*256 + (((j>>3)^(b&7))<<3) + (j&7))
#pragma unroll
  for (int c = 0; c < 2; ++c)
#pragma unroll
    for (int r = 0; r < 4; ++r) {
      int bb = q * 4 + r;
      int j  = jb + c * 16;
      int ad = bb * 256 + ((((j >> 3) ^ (bb & 7))) << 3) + (j & 7);
      hl[ad] = f2bs(h[c][r]);
    }

  // gx prefetch for t=0 (rows 4q..4q+3 at col g, 8B coalesced); single buffer
  const unsigned short* gpf = GX + ((size_t)wg * 768 + jb) * 16 + q * 4;
  ushort4 pf[6];
  pf[0] = *(const ushort4*)(gpf);
  pf[1] = *(const ushort4*)(gpf + 256);
  pf[2] = *(const ushort4*)(gpf + 4096);
  pf[3] = *(const ushort4*)(gpf + 4096 + 256);
  pf[4] = *(const ushort4*)(gpf + 8192);
  pf[5] = *(const ushort4*)(gpf + 8192 + 256);
  gpf += 196608;

  float* yp = Y + (size_t)(b0 + q * 4) * 256 + jb;
  __syncthreads();

  for (int t = 0; t < Tc; ++t) {
    // ---- gh = bf16(h) @ W_hh^T: 8x (ds_read af + ds_read w5 + 6 MFMA) ----
    f32x4 acc[6];
#pragma unroll
    for (int i = 0; i < 4; ++i) acc[i] = f32x4{0.f, 0.f, 0.f, 0.f};
    acc[4] = f32x4{bhn[0], bhn[0], bhn[0], bhn[0]};
    acc[5] = f32x4{bhn[1], bhn[1], bhn[1], bhn[1]};
    {
      const unsigned short* hb = hl + (t & 1) * 4096;
#pragma unroll
      for (int kt = 0; kt < 8; ++kt) {
        int ad = m * 256 + (((kt * 4 + q) ^ (m & 7)) << 3);
        bf16x8 af = *(const bf16x8*)(hb + ad);
        bf16x8 w5 = *(const bf16x8*)(wnl + kt * 512);
        acc[0] = __builtin_amdgcn_mfma_f32_16x16x32_bf16(af, bw[0][kt], acc[0], 0, 0, 0);
        acc[1] = __builtin_amdgcn_mfma_f32_16x16x32_bf16(af, bw[1][kt], acc[1], 0, 0, 0);
        acc[2] = __builtin_amdgcn_mfma_f32_16x16x32_bf16(af, bw[2][kt], acc[2], 0, 0, 0);
        acc[3] = __builtin_amdgcn_mfma_f32_16x16x32_bf16(af, bw[3][kt], acc[3], 0, 0, 0);
        acc[4] = __builtin_amdgcn_mfma_f32_16x16x32_bf16(af, bw[4][kt], acc[4], 0, 0, 0);
        acc[5] = __builtin_amdgcn_mfma_f32_16x16x32_bf16(af, w5, acc[5], 0, 0, 0);
      }
    }

    // ---- pointwise (exp2-prefolded), two c-phases; pf consumed & reloaded
    //      IN PLACE (no copies; reload lands during next step's MFMA) ----
    unsigned short* hw = hl + ((t + 1) & 1) * 4096;
#define GRU_CELL(C, PR4, PZ4, PN4)                                            \
    {                                                                         \
      _Pragma("unroll")                                                       \
      for (int r = 0; r < 4; ++r) {                                           \
        unsigned short pru = (r == 0) ? PR4.x : (r == 1) ? PR4.y : (r == 2) ? PR4.z : PR4.w; \
        unsigned short pzu = (r == 0) ? PZ4.x : (r == 1) ? PZ4.y : (r == 2) ? PZ4.z : PZ4.w; \
        unsigned short pnu = (r == 0) ? PN4.x : (r == 1) ? PN4.y : (r == 2) ? PN4.z : PN4.w; \
        float ir  = b2f(pru);                                                 \
        float iz  = b2f(pzu);                                                 \
        float inn = b2f(pnu);                                                 \
        float xr = ir + acc[C][r];                                            \
        float rr = __builtin_amdgcn_rcpf(1.f + __builtin_amdgcn_exp2f(-xr));  \
        float xz = iz + acc[2 + C][r];                                        \
        float zz = __builtin_amdgcn_rcpf(1.f + __builtin_amdgcn_exp2f(-xz));  \
        float nx = __builtin_fmaf(rr, acc[4 + C][r], inn);                    \
        float e2 = __builtin_amdgcn_exp2f(nx);                                \
        float nn = __builtin_fmaf(-2.f, __builtin_amdgcn_rcpf(1.f + e2), 1.f);\
        float hv = __builtin_fmaf(zz, h[C][r] - nn, nn);                      \
        h[C][r] = hv;                                                         \
        int bb = q * 4 + r;                                                   \
        int j  = jb + C * 16;                                                 \
        int ad = bb * 256 + ((((j >> 3) ^ (bb & 7))) << 3) + (j & 7);         \
        hw[ad] = f2bs(hv);                                                    \
        yp[r * 256 + C * 16] = hv;                                            \
      }                                                                       \
    }

    GRU_CELL(0, pf[0], pf[2], pf[4])
    if (t + 1 < Tc) {
      pf[0] = *(const ushort4*)(gpf);
      pf[2] = *(const ushort4*)(gpf + 4096);
      pf[4] = *(const ushort4*)(gpf + 8192);
    }
    GRU_CELL(1, pf[1], pf[3], pf[5])
    if (t + 1 < Tc) {
      pf[1] = *(const ushort4*)(gpf + 256);
      pf[3] = *(const ushort4*)(gpf + 4096 + 256);
      pf[5] = *(const ushort4*)(gpf + 8192 + 256);
      gpf += 196608;
    }
#undef GRU_CELL

    yp += 65536;
    asm volatile("s_waitcnt lgkmcnt(0)\n\ts_barrier" ::: "memory");
  }

  // carry out (f32) or finals (f32)
#pragma unroll
  for (int c = 0; c < 2; ++c)
#pragma unroll
    for (int r = 0; r < 4; ++r) {
      int bb = b0 + q * 4 + r;
      int j  = jb + c * 16;
      if (FIN) FIN[bb * 256 + j] = h[c][r];
      else     hcar[bb * 256 + j] = h[c][r];
    }
}

// ---------------------------------------------------------------------------
extern "C" void kernel_launch(void* const* d_in, const int* in_sizes, int n_in,
                              void* d_out, int out_size, void* d_ws, size_t ws_size,
                              hipStream_t stream) {
  const float* x    = (const float*)d_in[0]; // [512][256][128]
  const float* h0   = (const float*)d_in[1]; // [6][256][256]
  const float* Wih0 = (const float*)d_in[2]; // [768][128]
  const float* Wih  = (const float*)d_in[3]; // [5][768][256]
  const float* Whh  = (const float*)d_in[4]; // [6][768][256]
  const float* bih  = (const float*)d_in[5]; // [6][768]
  const float* bhh  = (const float*)d_in[6]; // [6][768]
  float* out = (float*)d_out;

  static int cfg = 0;
  if (!cfg) {
    hipFuncSetAttribute((const void*)gru_scan,
                        hipFuncAttributeMaxDynamicSharedMemorySize, 81920);
    cfg = 1;
  }

  // largest Tc (<=32) whose ws fits NLAY gx buffers + NLAY carries.
  // gx per layer = Tc*16*768*16*2 B = Tc*393216 B; hcar per layer = 256KB.
  int Tc = 32;
  while (Tc > 4) {
    size_t need = (size_t)NLAY * Tc * 393216ull + (size_t)NLAY * 262144ull;
    if (need <= ws_size) break;
    Tc >>= 1;
  }
  const int nch = 512 / Tc;
  const size_t gxElems = (size_t)Tc * 196608;   // ushorts per layer buffer

  char* ws = (char*)d_ws;
  unsigned short* gx0   = (unsigned short*)ws;
  float*          hcar0 = (float*)(ws + (size_t)NLAY * Tc * 393216ull);

  float* cur = out;                              // [512][256][256] f32
  float* fin = out + (size_t)512 * 256 * 256;    // [6][256][256] f32

  const int nslots = NLAY + nch - 1;
  for (int s = 0; s < nslots; ++s) {
    int lmin = s - (nch - 1); if (lmin < 0) lmin = 0;
    int lmax = (s < NLAY - 1) ? s : (NLAY - 1);

    GemmBatch gb = {};
    ScanBatch sb = {};
    int np = 0;
    for (int l = lmin; l <= lmax; ++l, ++np) {
      int c = s - l;
      gb.X[np]   = (l == 0) ? (x + (size_t)c * Tc * 256 * 128)
                            : (cur + (size_t)c * Tc * 65536);
      gb.W[np]   = (l == 0) ? Wih0 : (Wih + (size_t)(l - 1) * 768 * 256);
      gb.bih[np] = bih + l * 768;
      gb.bhh[np] = bhh + l * 768;
      gb.GX[np]  = gx0 + (size_t)l * gxElems;
      gb.K[np]   = (l == 0) ? 128 : 256;

      sb.GX[np]    = gb.GX[np];
      sb.Whh[np]   = Whh + (size_t)l * 768 * 256;
      sb.bhh[np]   = bhh + l * 768;
      sb.hcar[np]  = hcar0 + (size_t)l * 65536;
      sb.h0[np]    = h0 + (size_t)l * 65536;
      sb.Y[np]     = cur + (size_t)c * Tc * 65536;
      sb.FIN[np]   = (c == nch - 1) ? (fin + (size_t)l * 65536) : (float*)nullptr;
      sb.first[np] = (c == 0) ? 1 : 0;
    }
    sb.Tc = Tc;

    gx_gemm<<<dim3(Tc * 2, 6, np), dim3(256), 0, stream>>>(gb);
    gru_scan<<<dim3(16, np), dim3(512), 81920, stream>>>(sb);
  }
  (void)in_sizes; (void)n_in; (void)out_size; (void)ws_size;
}